// Round 1
// baseline (252.120 us; speedup 1.0000x reference)
//
#include <hip/hip_runtime.h>
#include <hip/hip_bf16.h>
#include <math.h>

typedef __attribute__((ext_vector_type(8))) short short8;
typedef __attribute__((ext_vector_type(4))) float f32x4;

__device__ __forceinline__ float b2f(unsigned short u) {
    union { unsigned int i; float f; } v; v.i = ((unsigned int)u) << 16; return v.f;
}
__device__ __forceinline__ unsigned short f2b(float f) {
    __hip_bfloat16 h = __float2bfloat16(f);
    return *reinterpret_cast<unsigned short*>(&h);
}

// ---------------------------------------------------------------------------
// K0: h_grid (128 img, 128 ch, 64x64) fp32  ->  ht (128 img, 4096 pix, 128 ch) bf16
// ---------------------------------------------------------------------------
__global__ __launch_bounds__(256) void transpose_h(const float* __restrict__ hg,
                                                   unsigned short* __restrict__ ht) {
    __shared__ float t[64][65];
    int bid = blockIdx.x;
    int n  = bid >> 7;          // 128 images
    int cb = (bid >> 6) & 1;    // 2 channel blocks of 64
    int pb = bid & 63;          // 64 pixel blocks of 64
    int tid = threadIdx.x;
    int j = tid & 63, i0 = tid >> 6;
    const float* src = hg + ((size_t)(n * 128 + cb * 64)) * 4096 + pb * 64;
#pragma unroll
    for (int ii = 0; ii < 16; ++ii) {
        int i = i0 + ii * 4;
        t[i][j] = src[(size_t)i * 4096 + j];
    }
    __syncthreads();
    int c = tid & 63, j0 = tid >> 6;
    unsigned short* dst = ht + ((size_t)n * 4096 + pb * 64) * 128 + cb * 64 + c;
#pragma unroll
    for (int jj = 0; jj < 16; ++jj) {
        int jr = j0 + jj * 4;
        dst[(size_t)jr * 128] = f2b(t[c][jr]);
    }
}

// ---------------------------------------------------------------------------
// K1: weights -> transposed bf16 ([out_unit][k], contiguous k for MFMA B-frags)
// ---------------------------------------------------------------------------
__global__ void prep_weights(const float* __restrict__ W0, const float* __restrict__ W1,
                             unsigned short* __restrict__ w0t, unsigned short* __restrict__ w1t) {
    int i = blockIdx.x * 256 + threadIdx.x;
    const int total0 = 128 * 384, total1 = 128 * 128;
    for (int idx = i; idx < total0; idx += gridDim.x * 256) {
        int j = idx / 384, k = idx - j * 384;
        w0t[idx] = f2b(W0[k * 128 + j]);
    }
    for (int idx = i; idx < total1; idx += gridDim.x * 256) {
        int j = idx >> 7, k = idx & 127;
        w1t[idx] = f2b(W1[k * 128 + j]);
    }
}

// ---------------------------------------------------------------------------
// K2: fused sample + fourier + MLP.  64 points/block, 256 threads (4 waves).
// LDS buf aliased: x-tile [64][392] bf16  ->  h0 [64][136] -> h1 [64][136]
// ---------------------------------------------------------------------------
#define XSTR 392
#define HSTR 136

__global__ __launch_bounds__(256) void fused_decoder(
    const unsigned short* __restrict__ ht,
    const float* __restrict__ xs, const float* __restrict__ ys,
    const float* __restrict__ Bm,
    const unsigned short* __restrict__ w0t, const float* __restrict__ b0,
    const unsigned short* __restrict__ w1t, const float* __restrict__ b1,
    const float* __restrict__ W2, const float* __restrict__ b2,
    float* __restrict__ out)
{
    __shared__ unsigned short buf[64 * XSTR];
    __shared__ int   cidx[64][4];
    __shared__ float cw[64][2];
    __shared__ float cxy[64][2];

    int tid = threadIdx.x;
    int n = blockIdx.x >> 5;              // image 0..127
    int pbase = (blockIdx.x & 31) * 64;   // point tile

    // ---- coord prep (mirror reference arithmetic exactly)
    if (tid < 64) {
        int gp = n * 2048 + pbase + tid;
        float x = xs[gp], y = ys[gp];
        cxy[tid][0] = x; cxy[tid][1] = y;
        float gx = 2.f * x - 1.f, gy = 2.f * y - 1.f;
        float px = (gx + 1.f) * 0.5f * 63.f;
        float py = (gy + 1.f) * 0.5f * 63.f;
        float x0 = fminf(fmaxf(floorf(px), 0.f), 63.f);
        float y0 = fminf(fmaxf(floorf(py), 0.f), 63.f);
        float x1 = fminf(x0 + 1.f, 63.f);
        float y1 = fminf(y0 + 1.f, 63.f);
        cw[tid][0] = px - x0; cw[tid][1] = py - y0;
        int xi0 = (int)x0, xi1 = (int)x1, yi0 = (int)y0, yi1 = (int)y1;
        cidx[tid][0] = yi0 * 64 + xi0; cidx[tid][1] = yi0 * 64 + xi1;
        cidx[tid][2] = yi1 * 64 + xi0; cidx[tid][3] = yi1 * 64 + xi1;
    }
    __syncthreads();

    // ---- phase A1: bilinear gather, 2 channels/thread (uint = 2 bf16)
    {
        const unsigned int* hti = (const unsigned int*)(ht + (size_t)n * 4096 * 128);
        int c2 = tid & 63;       // channel pair 0..63 -> channels 2c2, 2c2+1
        int ph = tid >> 6;       // wave id (uniform in wave)
        for (int p = ph; p < 64; p += 4) {
            float wx = cw[p][0], wy = cw[p][1];
            float ivx = 1.f - wx, ivy = 1.f - wy;
            unsigned int u00 = hti[cidx[p][0] * 64 + c2];
            unsigned int u01 = hti[cidx[p][1] * 64 + c2];
            unsigned int u10 = hti[cidx[p][2] * 64 + c2];
            unsigned int u11 = hti[cidx[p][3] * 64 + c2];
            float a00 = b2f(u00 & 0xffff), b00 = b2f(u00 >> 16);
            float a01 = b2f(u01 & 0xffff), b01 = b2f(u01 >> 16);
            float a10 = b2f(u10 & 0xffff), b10 = b2f(u10 >> 16);
            float a11 = b2f(u11 & 0xffff), b11 = b2f(u11 >> 16);
            float tA = a00 * ivx + a01 * wx;
            float bA = a10 * ivx + a11 * wx;
            float vA = tA * ivy + bA * wy;
            float tB = b00 * ivx + b01 * wx;
            float bB = b10 * ivx + b11 * wx;
            float vB = tB * ivy + bB * wy;
            unsigned int pack = (unsigned int)f2b(vA) | ((unsigned int)f2b(vB) << 16);
            *(unsigned int*)&buf[p * XSTR + 2 * c2] = pack;
        }
    }
    // ---- phase A2: fourier features via HW sin/cos (input in revolutions)
    {
        int f = tid & 127, ph = tid >> 7;    // ph uniform per wave
        float B0v = Bm[f], B1v = Bm[128 + f];
        for (int p = ph; p < 64; p += 2) {
            float t = cxy[p][0] * B0v + cxy[p][1] * B1v;   // proj = 2*pi*t
            float tf = t - floorf(t);
            float s, c;
            asm("v_sin_f32 %0, %1" : "=v"(s) : "v"(tf));
            asm("v_cos_f32 %0, %1" : "=v"(c) : "v"(tf));
            buf[p * XSTR + 128 + f] = f2b(s);
            buf[p * XSTR + 256 + f] = f2b(c);
        }
    }
    __syncthreads();

    int lane = tid & 63, w = tid >> 6;
    int lr = lane & 15, lg = lane >> 4;
    int wm = (w & 1) * 2;       // 2 m-tiles per wave
    int wn = (w >> 1) * 4;      // 4 n-tiles per wave

    // ================= layer 0: (64x384) @ (384x128) =================
    f32x4 acc[2][4];
#pragma unroll
    for (int mi = 0; mi < 2; ++mi)
#pragma unroll
        for (int nj = 0; nj < 4; ++nj) {
            float bv = b0[(wn + nj) * 16 + lr];
            acc[mi][nj] = (f32x4){bv, bv, bv, bv};
        }
#pragma unroll 2
    for (int ks = 0; ks < 12; ++ks) {
        short8 a[2], b[4];
#pragma unroll
        for (int mi = 0; mi < 2; ++mi)
            a[mi] = *(const short8*)&buf[((wm + mi) * 16 + lr) * XSTR + ks * 32 + lg * 8];
#pragma unroll
        for (int nj = 0; nj < 4; ++nj)
            b[nj] = *(const short8*)&w0t[((wn + nj) * 16 + lr) * 384 + ks * 32 + lg * 8];
#pragma unroll
        for (int mi = 0; mi < 2; ++mi)
#pragma unroll
            for (int nj = 0; nj < 4; ++nj)
                acc[mi][nj] = __builtin_amdgcn_mfma_f32_16x16x32_bf16(a[mi], b[nj], acc[mi][nj], 0, 0, 0);
    }
    __syncthreads();            // everyone done reading x-tile
    // relu -> h0 (bf16, stride HSTR), D-layout: row=(lane>>4)*4+r, col=lane&15
#pragma unroll
    for (int mi = 0; mi < 2; ++mi)
#pragma unroll
        for (int nj = 0; nj < 4; ++nj)
#pragma unroll
            for (int r = 0; r < 4; ++r) {
                float v = fmaxf(acc[mi][nj][r], 0.f);
                int row = (wm + mi) * 16 + lg * 4 + r;
                int col = (wn + nj) * 16 + lr;
                buf[row * HSTR + col] = f2b(v);
            }
    __syncthreads();

    // ================= layer 1: (64x128) @ (128x128) =================
#pragma unroll
    for (int mi = 0; mi < 2; ++mi)
#pragma unroll
        for (int nj = 0; nj < 4; ++nj) {
            float bv = b1[(wn + nj) * 16 + lr];
            acc[mi][nj] = (f32x4){bv, bv, bv, bv};
        }
#pragma unroll
    for (int ks = 0; ks < 4; ++ks) {
        short8 a[2], b[4];
#pragma unroll
        for (int mi = 0; mi < 2; ++mi)
            a[mi] = *(const short8*)&buf[((wm + mi) * 16 + lr) * HSTR + ks * 32 + lg * 8];
#pragma unroll
        for (int nj = 0; nj < 4; ++nj)
            b[nj] = *(const short8*)&w1t[((wn + nj) * 16 + lr) * 128 + ks * 32 + lg * 8];
#pragma unroll
        for (int mi = 0; mi < 2; ++mi)
#pragma unroll
            for (int nj = 0; nj < 4; ++nj)
                acc[mi][nj] = __builtin_amdgcn_mfma_f32_16x16x32_bf16(a[mi], b[nj], acc[mi][nj], 0, 0, 0);
    }
    __syncthreads();            // everyone done reading h0
#pragma unroll
    for (int mi = 0; mi < 2; ++mi)
#pragma unroll
        for (int nj = 0; nj < 4; ++nj)
#pragma unroll
            for (int r = 0; r < 4; ++r) {
                float v = fmaxf(acc[mi][nj][r], 0.f);
                int row = (wm + mi) * 16 + lg * 4 + r;
                int col = (wn + nj) * 16 + lr;
                buf[row * HSTR + col] = f2b(v);   // h1 overwrites h0
            }
    __syncthreads();

    // ================= layer 2: (64x128) @ (128x2), fp32 VALU =================
    if (tid < 128) {
        int p = tid >> 1, o = tid & 1;
        float acc2 = b2[o];
#pragma unroll 8
        for (int k = 0; k < 128; ++k)
            acc2 += b2f(buf[p * HSTR + k]) * W2[k * 2 + o];
        int gp = n * 2048 + pbase + p;
        if (o == 0) {
            out[gp * 2] = acc2;
        } else {
            float sp = (acc2 > 20.f) ? acc2 : log1pf(expf(acc2));
            out[gp * 2 + 1] = sp + 0.01f;
        }
    }
}

// ---------------------------------------------------------------------------
extern "C" void kernel_launch(void* const* d_in, const int* in_sizes, int n_in,
                              void* d_out, int out_size, void* d_ws, size_t ws_size,
                              hipStream_t stream) {
    const float* h_grid = (const float*)d_in[0];
    const float* xs = (const float*)d_in[1];
    const float* ys = (const float*)d_in[2];
    const float* Bm = (const float*)d_in[3];
    const float* W0 = (const float*)d_in[4];
    const float* b0 = (const float*)d_in[5];
    const float* W1 = (const float*)d_in[6];
    const float* b1 = (const float*)d_in[7];
    const float* W2 = (const float*)d_in[8];
    const float* b2 = (const float*)d_in[9];
    float* out = (float*)d_out;

    // workspace carve: ht (134217728 B) | w0t (98304 B) | w1t (32768 B)
    unsigned short* ht  = (unsigned short*)d_ws;
    unsigned short* w0t = (unsigned short*)((char*)d_ws + 134217728ull);
    unsigned short* w1t = w0t + 128 * 384;

    hipLaunchKernelGGL(transpose_h, dim3(16384), dim3(256), 0, stream, h_grid, ht);
    hipLaunchKernelGGL(prep_weights, dim3(64), dim3(256), 0, stream, W0, W1, w0t, w1t);
    hipLaunchKernelGGL(fused_decoder, dim3(4096), dim3(256), 0, stream,
                       ht, xs, ys, Bm, w0t, b0, w1t, b1, W2, b2, out);
}